// Round 7
// baseline (403.536 us; speedup 1.0000x reference)
//
#include <hip/hip_runtime.h>
#include <hip/hip_bf16.h>

#define B_ 2
#define T_ 1024
#define C_ 1024
#define H_ 16

typedef short bf16x8 __attribute__((ext_vector_type(8)));
typedef float f32x4 __attribute__((ext_vector_type(4)));

#define MFMA16(a, b, c) __builtin_amdgcn_mfma_f32_16x16x32_bf16(a, b, c, 0, 0, 0)

__device__ inline short f2bf(float x) {
    union { __hip_bfloat16 h; short s; } u;
    u.h = __float2bfloat16(x);
    return u.s;
}

__device__ inline void gl_lds16(const void* g, void* l) {
    __builtin_amdgcn_global_load_lds(
        (const __attribute__((address_space(1))) unsigned int*)g,
        (__attribute__((address_space(3))) unsigned int*)l, 16, 0, 0);
}

// ---------------------------------------------------------------------------
// Kernel: x (fp32) -> xb (bf16), flat. 2M elems, 8/thread.
// ---------------------------------------------------------------------------
__global__ __launch_bounds__(256) void cvt_x(const float* __restrict__ x,
                                             short* __restrict__ xb) {
    int idx = (blockIdx.x * 256 + threadIdx.x) * 8;
    float4 a = *(const float4*)(x + idx);
    float4 b = *(const float4*)(x + idx + 4);
    bf16x8 v;
    v[0] = f2bf(a.x); v[1] = f2bf(a.y); v[2] = f2bf(a.z); v[3] = f2bf(a.w);
    v[4] = f2bf(b.x); v[5] = f2bf(b.y); v[6] = f2bf(b.z); v[7] = f2bf(b.w);
    *(bf16x8*)(xb + idx) = v;
}

// ---------------------------------------------------------------------------
// Kernel: generic fp32->bf16 64x64 tile transpose.
//   dst[(g*1024 + r)*1024 + c] = bf16(src[(g*1024 + c)*1024 + r])
// Used for Wt (g = h, grid 4096) AND xbT (g = b, grid 512).
// ---------------------------------------------------------------------------
__global__ __launch_bounds__(256) void cvt_w(const float* __restrict__ W,
                                             short* __restrict__ Wt) {
    __shared__ float T[64][65];
    const int bid = blockIdx.x;
    const int nb = bid & 15, cb = (bid >> 4) & 15, h = bid >> 8;
    const int t = threadIdx.x;
    const int c0 = cb * 64, n0 = nb * 64;
    const float* src = W + (size_t)(h * 1024 + c0) * 1024 + n0;
    {
        const int cl = t >> 4, nl = (t & 15) * 4;
#pragma unroll
        for (int r = 0; r < 4; ++r) {
            float4 v = *(const float4*)(src + (size_t)(cl + r * 16) * 1024 + nl);
            T[cl + r * 16][nl + 0] = v.x;
            T[cl + r * 16][nl + 1] = v.y;
            T[cl + r * 16][nl + 2] = v.z;
            T[cl + r * 16][nl + 3] = v.w;
        }
    }
    __syncthreads();
    {
        short* dst = Wt + (size_t)(h * 1024 + n0) * 1024 + c0;
        const int nl = t >> 3, cl8 = (t & 7) * 8;
#pragma unroll
        for (int r = 0; r < 2; ++r) {
            const int n = nl + r * 32;
            bf16x8 o;
#pragma unroll
            for (int j = 0; j < 8; ++j) o[j] = f2bf(T[cl8 + j][n]);
            *(bf16x8*)(dst + (size_t)n * 1024 + cl8) = o;
        }
    }
}

// ---------------------------------------------------------------------------
// Kernel: attn_po v4 — O[b][t][h][c] = softmax(mask(QK^T)/4) @ x  (V = xbT).
// One 64-row tile per block: 512 blocks = 32 bh * 16 tiles (tb pairing
// rest<8 ? rest : 23-rest keeps per-CU total at 17 chunks).
// ONE change vs v3 (155 us, TLP-insensitive across rounds 0-6):
// __launch_bounds__(512, 1) -> VGPR cap 256 (2 waves/SIMD), enough to HOLD
// the 16 prefetched V fragments (acc 128 + vf 64 + misc ~= 240 VGPR).
// All 16 V loads issue at the TOP of each chunk iteration, before QK —
// their ~300cy L2 latency hides under QK MFMA + softmax, and PV becomes a
// pure register MFMA chain. Rounds 3/5 failed this hoist ONLY because the
// VGPR cap (128/64) forced remat/spill — watch VGPR_Count ~240, scratch 0.
// Plain bf16 stores to O (each (b,h,t) owned by one block).
// ---------------------------------------------------------------------------
__global__ __launch_bounds__(512, 1) void attn_po(const short* __restrict__ xb,
                                                  const short* __restrict__ xbT,
                                                  short* __restrict__ O) {
    __shared__ short Pb[2][64][72];     // probs bf16, double-buffered
    __shared__ float row_al[2][64];
    __shared__ float row_l[64];
    __shared__ int   flags[2][4];

    const int tid = threadIdx.x;
    const int bh = blockIdx.x & 31;                  // XCD-pinned (b,h)
    const int rest = blockIdx.x >> 5;                // 0..15
    const int tb = (rest < 8) ? rest : 23 - rest;    // pair long+short tiles
    const int b = bh >> 4, h = bh & 15;
    const int lane = tid & 63, q = lane >> 4, l16 = lane & 15;
    const int w = tid >> 6;
    const int g = w & 3;          // QK row-group
    const int nw = w * 128;       // PV channel base
    const short* xbb = xb + ((size_t)b << 20);
    const short* vtb = xbT + ((size_t)b << 20);   // [c][s], s contiguous

    const int t0 = tb * 64;
    const int nch = tb + 1;

    f32x4 acc[4][8];
#pragma unroll
    for (int mt = 0; mt < 4; ++mt)
#pragma unroll
        for (int nt = 0; nt < 8; ++nt) acc[mt][nt] = (f32x4){0.f, 0.f, 0.f, 0.f};
    float m_r[4], l_r[4];
#pragma unroll
    for (int r = 0; r < 4; ++r) { m_r[r] = -3.0e38f; l_r[r] = 0.f; }

    bf16x8 qf[2];
    if (w < 4) {
#pragma unroll
        for (int ks = 0; ks < 2; ++ks)
            qf[ks] = *(const bf16x8*)(xbb + (size_t)(t0 + g * 16 + l16) * 1024 +
                                      h * 64 + ks * 32 + q * 8);
    }

    for (int ci = -1; ci < nch; ++ci) {
        __syncthreads();
        const int cc = ci + 1;

        // ---- V prefetch for PV(ci): issue ALL 16 loads first (L2-hot xbT).
        bf16x8 vf[8][2];
        const int s0p = (ci <= 0) ? t0 : (ci - 1) * 64;
        if (ci >= 0) {
#pragma unroll
            for (int nt = 0; nt < 8; ++nt)
#pragma unroll
                for (int ks = 0; ks < 2; ++ks)
                    vf[nt][ks] = *(const bf16x8*)(vtb +
                        (size_t)(nw + nt * 16 + l16) * 1024 + s0p + ks * 32 + q * 8);
        }

        // ---- QK^T + in-register online softmax (waves 0-3), covers V lat.
        if (w < 4 && cc < nch) {
            const int s0 = (cc == 0) ? t0 : (cc - 1) * 64;
            const int par = cc & 1;
            f32x4 sf[4];
#pragma unroll
            for (int st = 0; st < 4; ++st) sf[st] = (f32x4){0.f, 0.f, 0.f, 0.f};
#pragma unroll
            for (int st = 0; st < 4; ++st)
#pragma unroll
                for (int ks = 0; ks < 2; ++ks) {
                    bf16x8 kf = *(const bf16x8*)(xbb +
                        (size_t)(s0 + st * 16 + l16) * 1024 + h * 64 + ks * 32 + q * 8);
                    sf[st] = MFMA16(qf[ks], kf, sf[st]);
                }
            float mx[4] = {-3.0e38f, -3.0e38f, -3.0e38f, -3.0e38f};
#pragma unroll
            for (int st = 0; st < 4; ++st)
#pragma unroll
                for (int r = 0; r < 4; ++r) {
                    float v = sf[st][r] * 0.25f;
                    if (cc == 0 && (s0 + st * 16 + l16) > (t0 + g * 16 + q * 4 + r))
                        v = -3.0e38f;
                    sf[st][r] = v;
                    mx[r] = fmaxf(mx[r], v);
                }
#pragma unroll
            for (int r = 0; r < 4; ++r) {
                mx[r] = fmaxf(mx[r], __shfl_xor(mx[r], 1));
                mx[r] = fmaxf(mx[r], __shfl_xor(mx[r], 2));
                mx[r] = fmaxf(mx[r], __shfl_xor(mx[r], 4));
                mx[r] = fmaxf(mx[r], __shfl_xor(mx[r], 8));
            }
            float sum[4], al[4];
            int upd = 0;
#pragma unroll
            for (int r = 0; r < 4; ++r) {
                float m_new = fmaxf(m_r[r], mx[r]);
                al[r] = __expf(m_r[r] - m_new);
                upd |= (m_new > m_r[r]) ? 1 : 0;
                m_r[r] = m_new;
                sum[r] = 0.f;
            }
#pragma unroll
            for (int st = 0; st < 4; ++st)
#pragma unroll
                for (int r = 0; r < 4; ++r) {
                    float pv = __expf(sf[st][r] - m_r[r]);
                    sum[r] += pv;
                    Pb[par][g * 16 + q * 4 + r][st * 16 + l16] = f2bf(pv);
                }
#pragma unroll
            for (int r = 0; r < 4; ++r) {
                sum[r] += __shfl_xor(sum[r], 1);
                sum[r] += __shfl_xor(sum[r], 2);
                sum[r] += __shfl_xor(sum[r], 4);
                sum[r] += __shfl_xor(sum[r], 8);
                l_r[r] = l_r[r] * al[r] + sum[r];
            }
            if (l16 == 0) {
#pragma unroll
                for (int r = 0; r < 4; ++r) row_al[par][g * 16 + q * 4 + r] = al[r];
            }
            int any_upd = __any(upd);
            if (lane == 0) flags[par][g] = any_upd;
        }

        // ---- PV for chunk ci: pure register MFMA chain (vf prefetched).
        if (ci >= 0) {
            const int par = ci & 1;
            if (flags[par][0] | flags[par][1] | flags[par][2] | flags[par][3]) {
#pragma unroll
                for (int mt = 0; mt < 4; ++mt) {
                    float a0 = row_al[par][mt * 16 + q * 4 + 0];
                    float a1 = row_al[par][mt * 16 + q * 4 + 1];
                    float a2 = row_al[par][mt * 16 + q * 4 + 2];
                    float a3 = row_al[par][mt * 16 + q * 4 + 3];
#pragma unroll
                    for (int nt = 0; nt < 8; ++nt) {
                        acc[mt][nt][0] *= a0;
                        acc[mt][nt][1] *= a1;
                        acc[mt][nt][2] *= a2;
                        acc[mt][nt][3] *= a3;
                    }
                }
            }
            bf16x8 pf[4][2];
#pragma unroll
            for (int mt = 0; mt < 4; ++mt)
#pragma unroll
                for (int ks = 0; ks < 2; ++ks)
                    pf[mt][ks] = *(bf16x8*)&Pb[par][mt * 16 + l16][ks * 32 + q * 8];
#pragma unroll
            for (int nt = 0; nt < 8; ++nt)
#pragma unroll
                for (int ks = 0; ks < 2; ++ks)
#pragma unroll
                    for (int mt = 0; mt < 4; ++mt)
                        acc[mt][nt] = MFMA16(pf[mt][ks], vf[nt][ks], acc[mt][nt]);
        }
    }

    // Epilogue: share row sums, normalize, PLAIN bf16 stores to O.
    if (w < 4 && l16 == 0) {
#pragma unroll
        for (int r = 0; r < 4; ++r) row_l[g * 16 + q * 4 + r] = l_r[r];
    }
    __syncthreads();
    short* ob = O + ((((size_t)(b * 1024 + t0) * 16) + h) << 10);
#pragma unroll
    for (int mt = 0; mt < 4; ++mt) {
        float i0 = 1.f / row_l[mt * 16 + q * 4 + 0];
        float i1 = 1.f / row_l[mt * 16 + q * 4 + 1];
        float i2 = 1.f / row_l[mt * 16 + q * 4 + 2];
        float i3 = 1.f / row_l[mt * 16 + q * 4 + 3];
#pragma unroll
        for (int nt = 0; nt < 8; ++nt) {
            size_t base = (size_t)(mt * 16 + q * 4) * 16384 + nw + nt * 16 + l16;
            ob[base]         = f2bf(acc[mt][nt][0] * i0);
            ob[base + 16384] = f2bf(acc[mt][nt][1] * i1);
            ob[base + 32768] = f2bf(acc[mt][nt][2] * i2);
            ob[base + 49152] = f2bf(acc[mt][nt][3] * i3);
        }
    }
}

// ---------------------------------------------------------------------------
// Kernel: ogemm v3 — out[m][n] += O[m][k] * Wt[k->(h,c)][n].
// M=2048, N=1024, K=16384. ONE change vs proven v1 (176 us, MfmaUtil 16%,
// 2 blocks/CU): split-K 4->8 -> grid 1024 = 4 blocks/CU. Four independent
// barrier groups per CU overlap each other's staging/vmcnt drains (m97 runs
// at 3-4 blocks/CU). BK=32 and block mapping otherwise identical; round-5's
// regression bundled this with BK=64 + swizzle, so this isolates it.
// Cost: atomics 8.4M -> 16.8M (epilogue only; out pre-zeroed).
// ---------------------------------------------------------------------------
__global__ __launch_bounds__(256, 4) void ogemm(const short* __restrict__ O,
                                                const short* __restrict__ Wt,
                                                float* __restrict__ out) {
    __shared__ short Al[4][128][8];   // [kgrp][m][8k]  8 KiB
    __shared__ short Bl[4][128][8];   // [kgrp][n][8k]  8 KiB

    const int bid = blockIdx.x;
    const int kq = bid >> 7, m_t = (bid >> 3) & 15, n_t = bid & 7;
    const int m0 = m_t * 128, n0 = n_t * 128;
    const int t = threadIdx.x;
    const int lane = t & 63, q = lane >> 4, l16 = lane & 15;
    const int wv = t >> 6;
    const int wm = (wv & 1) * 64, wn = (wv >> 1) * 64;

    const short* Ab = O + (size_t)m0 * 16384;
    const int srow = t & 127, skg = t >> 7;        // staging row / k-group

    char* al_base = (char*)&Al[0][0][0] + (size_t)t * 16;
    char* bl_base = (char*)&Bl[0][0][0] + (size_t)t * 16;

    f32x4 acc[4][4];
#pragma unroll
    for (int i = 0; i < 4; ++i)
#pragma unroll
        for (int j = 0; j < 4; ++j) acc[i][j] = (f32x4){0.f, 0.f, 0.f, 0.f};

    const int kbase = kq * 2048;                   // 2048 K per split (8 way)
    for (int kk = 0; kk < 2048; kk += 32) {
        const int k0 = kbase + kk;
        const int h = k0 >> 10, c0 = k0 & 1023;
        const short* Bb = Wt + ((size_t)h << 20) + (size_t)n0 * 1024 + c0;
        __syncthreads();
        gl_lds16(Ab + (size_t)srow * 16384 + k0 + skg * 8, al_base);
        gl_lds16(Ab + (size_t)srow * 16384 + k0 + (skg + 2) * 8, al_base + 4096);
        gl_lds16(Bb + (size_t)srow * 1024 + skg * 8, bl_base);
        gl_lds16(Bb + (size_t)srow * 1024 + (skg + 2) * 8, bl_base + 4096);
        __syncthreads();
        bf16x8 af[4], bfr[4];
#pragma unroll
        for (int i = 0; i < 4; ++i) af[i] = *(bf16x8*)&Al[q][wm + i * 16 + l16][0];
#pragma unroll
        for (int j = 0; j < 4; ++j) bfr[j] = *(bf16x8*)&Bl[q][wn + j * 16 + l16][0];
#pragma unroll
        for (int i = 0; i < 4; ++i)
#pragma unroll
            for (int j = 0; j < 4; ++j)
                acc[i][j] = MFMA16(af[i], bfr[j], acc[i][j]);
    }

    // Epilogue: out[m][n] atomic add (split-K partial).
#pragma unroll
    for (int i = 0; i < 4; ++i)
#pragma unroll
        for (int j = 0; j < 4; ++j)
#pragma unroll
            for (int r = 0; r < 4; ++r) {
                int m = m0 + wm + i * 16 + q * 4 + r;
                int n = n0 + wn + j * 16 + l16;
                atomicAdd(out + (size_t)m * 1024 + n, acc[i][j][r]);
            }
}

// ---------------------------------------------------------------------------
// Fallback path kernels (round-0 proven): zgemm_fast/zgemm_sm + atomic attn.
// ---------------------------------------------------------------------------
__global__ __launch_bounds__(256, 4) void zgemm_fast(const short* __restrict__ xb,
                                                     const short* __restrict__ Wt,
                                                     short* __restrict__ ZT) {
    __shared__ short Al[4][128][8];
    __shared__ short Bl[4][128][8];

    const int bid = blockIdx.x;
    const int n_t = bid & 7, h = (bid >> 3) & 15, s_t = bid >> 7;
    const int n0 = n_t * 128, s0g = s_t * 128;
    const int t = threadIdx.x;
    const int lane = t & 63, q = lane >> 4, l16 = lane & 15;
    const int wv = t >> 6;
    const int wm = (wv & 1) * 64, wn = (wv >> 1) * 64;

    const short* Ab = Wt + ((size_t)h * 1024 + n0) * 1024;
    const short* Bb = xb + (size_t)s0g * 1024;
    const int srow = t & 127, skg = t >> 7;

    char* al_base = (char*)&Al[0][0][0] + (size_t)t * 16;
    char* bl_base = (char*)&Bl[0][0][0] + (size_t)t * 16;

    f32x4 acc[4][4];
#pragma unroll
    for (int i = 0; i < 4; ++i)
#pragma unroll
        for (int j = 0; j < 4; ++j) acc[i][j] = (f32x4){0.f, 0.f, 0.f, 0.f};

    for (int k0 = 0; k0 < 1024; k0 += 32) {
        __syncthreads();
        gl_lds16(Ab + (size_t)srow * 1024 + k0 + skg * 8, al_base);
        gl_lds16(Ab + (size_t)srow * 1024 + k0 + (skg + 2) * 8, al_base + 4096);
        gl_lds16(Bb + (size_t)srow * 1024 + k0 + skg * 8, bl_base);
        gl_lds16(Bb + (size_t)srow * 1024 + k0 + (skg + 2) * 8, bl_base + 4096);
        __syncthreads();
        bf16x8 af[4], bfr[4];
#pragma unroll
        for (int i = 0; i < 4; ++i) af[i] = *(bf16x8*)&Al[q][wm + i * 16 + l16][0];
#pragma unroll
        for (int j = 0; j < 4; ++j) bfr[j] = *(bf16x8*)&Bl[q][wn + j * 16 + l16][0];
#pragma unroll
        for (int i = 0; i < 4; ++i)
#pragma unroll
            for (int j = 0; j < 4; ++j)
                acc[i][j] = MFMA16(af[i], bfr[j], acc[i][j]);
    }

    const int b = s0g >> 10, s_in0 = s0g & 1023;
    short* zb = ZT + ((size_t)(b * 16 + h) << 20);
#pragma unroll
    for (int i = 0; i < 4; ++i)
#pragma unroll
        for (int j = 0; j < 4; ++j)
#pragma unroll
            for (int r = 0; r < 4; ++r) {
                int n = n0 + wm + i * 16 + q * 4 + r;
                int s = s_in0 + wn + j * 16 + l16;
                zb[(size_t)n * 1024 + s] = f2bf(acc[i][j][r]);
            }
}

#define ZPAD 40

__global__ __launch_bounds__(256, 2) void zgemm_sm(const short* __restrict__ xb,
                                                   const float* __restrict__ W,
                                                   short* __restrict__ ZT) {
    __shared__ short Wts[128 * ZPAD];
    __shared__ short Xs[2][128 * ZPAD];

    const int tid = threadIdx.x;
    const int bs = blockIdx.x & 7;
    const int bn = (blockIdx.x >> 3) & 7;
    const int h  = blockIdx.x >> 6;
    const int s0 = bs * 128, n0 = bn * 128;
    const int lane = tid & 63, q = lane >> 4, l16 = lane & 15;
    const int w = tid >> 6, bw = w >> 1, sh = w & 1;

    f32x4 acc[8][4];
#pragma unroll
    for (int i = 0; i < 8; ++i)
#pragma unroll
        for (int j = 0; j < 4; ++j) acc[i][j] = (f32x4){0.f, 0.f, 0.f, 0.f};

    for (int k0 = 0; k0 < 1024; k0 += 32) {
        __syncthreads();
#pragma unroll
        for (int r = 0; r < 2; ++r) {
            const int c2 = ((tid >> 5) << 1) + (r << 4);
            const float* w0p = W + (size_t)(h * 1024 + k0 + c2) * 1024 + n0;
            const float* w1p = w0p + 1024;
#pragma unroll
            for (int i = 0; i < 4; ++i) {
                const int n = (tid & 31) + (i << 5);
                float wa = w0p[n], wb = w1p[n];
                unsigned u = (unsigned)(unsigned short)f2bf(wa) |
                             ((unsigned)(unsigned short)f2bf(wb) << 16);
                *(unsigned*)&Wts[n * ZPAD + c2] = u;
            }
        }
#pragma unroll
        for (int i = 0; i < 4; ++i) {
            const int id = tid + (i << 8);
            const int b2 = id >> 9, s = (id >> 2) & 127, cg = id & 3;
            bf16x8 v = *(const bf16x8*)(xb + (size_t)b2 * (T_ * C_) +
                                        (size_t)(s0 + s) * 1024 + k0 + cg * 8);
            *(bf16x8*)&Xs[b2][s * ZPAD + cg * 8] = v;
        }
        __syncthreads();

        bf16x8 af[8], bfr[4];
#pragma unroll
        for (int nt = 0; nt < 8; ++nt)
            af[nt] = *(bf16x8*)&Wts[(nt * 16 + l16) * ZPAD + q * 8];
#pragma unroll
        for (int st = 0; st < 4; ++st)
            bfr[st] = *(bf16x8*)&Xs[bw][(sh * 64 + st * 16 + l16) * ZPAD + q * 8];
#pragma unroll
        for (int nt = 0; nt < 8; ++nt)
#pragma unroll
            for (int st = 0; st < 4; ++st)
                acc[nt][st] = MFMA16(af[nt], bfr[st], acc[nt][st]);
    }

    short* zb = ZT + (size_t)(bw * 16 + h) * (1024 * 1024);
#pragma unroll
    for (int nt = 0; nt < 8; ++nt)
#pragma unroll
        for (int st = 0; st < 4; ++st)
#pragma unroll
            for (int r = 0; r < 4; ++r) {
                int n_abs = n0 + nt * 16 + q * 4 + r;
                int s_abs = s0 + sh * 64 + st * 16 + l16;
                zb[(size_t)n_abs * 1024 + s_abs] = f2bf(acc[nt][st][r]);
            }
}

__global__ __launch_bounds__(512, 2) void attn(const short* __restrict__ xb,
                                               const short* __restrict__ ZT,
                                               float* __restrict__ out) {
    __shared__ short Pb[2][64][72];
    __shared__ float row_al[2][64];
    __shared__ float row_l[64];
    __shared__ int   flags[2][4];

    const int tid = threadIdx.x;
    const int bh = blockIdx.x & 31, p = blockIdx.x >> 5;
    const int b = bh >> 4, h = bh & 15;
    const int lane = tid & 63, q = lane >> 4, l16 = lane & 15;
    const int w = tid >> 6;
    const int g = w & 3;
    const int nw = w * 128;
    const short* xbb = xb + ((size_t)b << 20);
    const short* ztb = ZT + ((size_t)(b * 16 + h) << 20);

    const int tiles[2] = { p, 15 - p };
    for (int ti = 0; ti < 2; ++ti) {
        const int tb = tiles[ti];
        const int t0 = tb * 64;
        const int nch = tb + 1;

        f32x4 acc[4][8];
#pragma unroll
        for (int mt = 0; mt < 4; ++mt)
#pragma unroll
            for (int nt = 0; nt < 8; ++nt) acc[mt][nt] = (f32x4){0.f, 0.f, 0.f, 0.f};
        float m_r[4], l_r[4];
#pragma unroll
        for (int r = 0; r < 4; ++r) { m_r[r] = -3.0e38f; l_r[r] = 0.f; }

        bf16x8 qf[2];
        if (w < 4) {
#pragma unroll
            for (int ks = 0; ks < 2; ++ks)
                qf[ks] = *(const bf16x8*)(xbb + (size_t)(t0 + g * 16 + l16) * 1024 +
                                          h * 64 + ks * 32 + q * 8);
        }

        for (int ci = -1; ci < nch; ++ci) {
            __syncthreads();
            const int cc = ci + 1;
            if (w < 4 && cc < nch) {
                const int s0 = (cc == 0) ? t0 : (cc - 1) * 64;
                const int par = cc & 1;
                f32x4 sf[4];
#pragma unroll
                for (int st = 0; st < 4; ++st) sf[st] = (f32x4){0.f, 0.f, 0.f, 0.f};
#pragma unroll
                for (int st = 0; st < 4; ++st)
#pragma unroll
                    for (int ks = 0; ks < 2; ++ks) {
                        bf16x8 kf = *(const bf16x8*)(xbb +
                            (size_t)(s0 + st * 16 + l16) * 1024 + h * 64 + ks * 32 + q * 8);
                        sf[st] = MFMA16(qf[ks], kf, sf[st]);
                    }
                float mx[4] = {-3.0e38f, -3.0e38f, -3.0e38f, -3.0e38f};
#pragma unroll
                for (int st = 0; st < 4; ++st)
#pragma unroll
                    for (int r = 0; r < 4; ++r) {
                        float v = sf[st][r] * 0.25f;
                        if (cc == 0 && (s0 + st * 16 + l16) > (t0 + g * 16 + q * 4 + r))
                            v = -3.0e38f;
                        sf[st][r] = v;
                        mx[r] = fmaxf(mx[r], v);
                    }
#pragma unroll
                for (int r = 0; r < 4; ++r) {
                    mx[r] = fmaxf(mx[r], __shfl_xor(mx[r], 1));
                    mx[r] = fmaxf(mx[r], __shfl_xor(mx[r], 2));
                    mx[r] = fmaxf(mx[r], __shfl_xor(mx[r], 4));
                    mx[r] = fmaxf(mx[r], __shfl_xor(mx[r], 8));
                }
                float sum[4], al[4];
                int upd = 0;
#pragma unroll
                for (int r = 0; r < 4; ++r) {
                    float m_new = fmaxf(m_r[r], mx[r]);
                    al[r] = __expf(m_r[r] - m_new);
                    upd |= (m_new > m_r[r]) ? 1 : 0;
                    m_r[r] = m_new;
                    sum[r] = 0.f;
                }
#pragma unroll
                for (int st = 0; st < 4; ++st)
#pragma unroll
                    for (int r = 0; r < 4; ++r) {
                        float pv = __expf(sf[st][r] - m_r[r]);
                        sum[r] += pv;
                        Pb[par][g * 16 + q * 4 + r][st * 16 + l16] = f2bf(pv);
                    }
#pragma unroll
                for (int r = 0; r < 4; ++r) {
                    sum[r] += __shfl_xor(sum[r], 1);
                    sum[r] += __shfl_xor(sum[r], 2);
                    sum[r] += __shfl_xor(sum[r], 4);
                    sum[r] += __shfl_xor(sum[r], 8);
                    l_r[r] = l_r[r] * al[r] + sum[r];
                }
                if (l16 == 0) {
#pragma unroll
                    for (int r = 0; r < 4; ++r) row_al[par][g * 16 + q * 4 + r] = al[r];
                }
                int any_upd = __any(upd);
                if (lane == 0) flags[par][g] = any_upd;
            }
            if (ci >= 0) {
                const int par = ci & 1;
                if (flags[par][0] | flags[par][1] | flags[par][2] | flags[par][3]) {
#pragma unroll
                    for (int mt = 0; mt < 4; ++mt) {
                        float a0 = row_al[par][mt * 16 + q * 4 + 0];
                        float a1 = row_al[par][mt * 16 + q * 4 + 1];
                        float a2 = row_al[par][mt * 16 + q * 4 + 2];
                        float a3 = row_al[par][mt * 16 + q * 4 + 3];
#pragma unroll
                        for (int nt = 0; nt < 8; ++nt) {
                            acc[mt][nt][0] *= a0;
                            acc[mt][nt][1] *= a1;
                            acc[mt][nt][2] *= a2;
                            acc[mt][nt][3] *= a3;
                        }
                    }
                }
                bf16x8 pf[4][2];
#pragma unroll
                for (int mt = 0; mt < 4; ++mt)
#pragma unroll
                    for (int ks = 0; ks < 2; ++ks)
                        pf[mt][ks] = *(bf16x8*)&Pb[par][mt * 16 + l16][ks * 32 + q * 8];
                const int s0p = (ci == 0) ? t0 : (ci - 1) * 64;
#pragma unroll
                for (int nt = 0; nt < 8; ++nt)
#pragma unroll
                    for (int ks = 0; ks < 2; ++ks) {
                        bf16x8 vf = *(const bf16x8*)(ztb +
                            (size_t)(nw + nt * 16 + l16) * 1024 + s0p + ks * 32 + q * 8);
#pragma unroll
                        for (int mt = 0; mt < 4; ++mt)
                            acc[mt][nt] = MFMA16(pf[mt][ks], vf, acc[mt][nt]);
                    }
            }
        }

        if (w < 4 && l16 == 0) {
#pragma unroll
            for (int r = 0; r < 4; ++r) row_l[g * 16 + q * 4 + r] = l_r[r];
        }
        __syncthreads();
#pragma unroll
        for (int mt = 0; mt < 4; ++mt) {
            float i0 = 1.f / row_l[mt * 16 + q * 4 + 0];
            float i1 = 1.f / row_l[mt * 16 + q * 4 + 1];
            float i2 = 1.f / row_l[mt * 16 + q * 4 + 2];
            float i3 = 1.f / row_l[mt * 16 + q * 4 + 3];
#pragma unroll
            for (int nt = 0; nt < 8; ++nt) {
                size_t base = (size_t)(b * 1024 + t0 + mt * 16 + q * 4) * 1024 +
                              nw + nt * 16 + l16;
                atomicAdd(out + base,            acc[mt][nt][0] * i0);
                atomicAdd(out + base + 1024,     acc[mt][nt][1] * i1);
                atomicAdd(out + base + 2048,     acc[mt][nt][2] * i2);
                atomicAdd(out + base + 3072,     acc[mt][nt][3] * i3);
            }
        }
        __syncthreads();
    }
}

// ---------------------------------------------------------------------------
extern "C" void kernel_launch(void* const* d_in, const int* in_sizes, int n_in,
                              void* d_out, int out_size, void* d_ws, size_t ws_size,
                              hipStream_t stream) {
    const float* x = (const float*)d_in[0];
    // d_in[1] (mask) recomputed analytically.
    const float* W = (const float*)d_in[2];
    float* out = (float*)d_out;

    hipMemsetAsync(d_out, 0, (size_t)B_ * T_ * C_ * sizeof(float), stream);

    if (ws_size >= (size_t)104 * 1024 * 1024) {
        // O = P@x per head (plain stores), then one long-K GEMM.
        // ws layout (shorts): xb[0,2M) xbT[2M,4M) Wt[4M,20M) O[20M,52M)
        short* xb  = (short*)d_ws;
        short* xbT = xb + (size_t)2 * 1024 * 1024;
        short* Wt  = xb + (size_t)4 * 1024 * 1024;
        short* O   = xb + (size_t)20 * 1024 * 1024;

        cvt_x<<<(B_ * T_ * C_) / (256 * 8), 256, 0, stream>>>(x, xb);
        cvt_w<<<B_ * 16 * 16, 256, 0, stream>>>(x, xbT);   // xbT[b][c][s]
        cvt_w<<<16 * 16 * 16, 256, 0, stream>>>(W, Wt);    // Wt[h][n][c]
        attn_po<<<512, 512, 0, stream>>>(xb, xbT, O);
        ogemm<<<8 * 16 * 8, 256, 0, stream>>>(O, Wt, out);
    } else {
        // Fallback: round-0 proven pipeline.
        short* xb = (short*)d_ws;                              // 4 MiB
        short* ZT = (short*)d_ws + (size_t)B_ * T_ * C_;       // 64 MiB
        short* Wt = ZT + (size_t)B_ * H_ * 1024 * 1024;        // 32 MiB

        const bool big_ws = ws_size >= (size_t)100 * 1024 * 1024;
        cvt_x<<<(B_ * T_ * C_) / (256 * 8), 256, 0, stream>>>(x, xb);
        if (big_ws) {
            cvt_w<<<16 * 16 * 16, 256, 0, stream>>>(W, Wt);
            zgemm_fast<<<16 * 16 * 8, 256, 0, stream>>>(xb, Wt, ZT);
        } else {
            zgemm_sm<<<H_ * 8 * 8, 256, 0, stream>>>(xb, W, ZT);
        }
        attn<<<256, 512, 0, stream>>>(xb, ZT, out);
    }
}

// Round 8
// 355.243 us; speedup vs baseline: 1.1359x; 1.1359x over previous
//
#include <hip/hip_runtime.h>
#include <hip/hip_bf16.h>

#define B_ 2
#define T_ 1024
#define C_ 1024
#define H_ 16

typedef short bf16x8 __attribute__((ext_vector_type(8)));
typedef float f32x4 __attribute__((ext_vector_type(4)));

#define MFMA16(a, b, c) __builtin_amdgcn_mfma_f32_16x16x32_bf16(a, b, c, 0, 0, 0)

__device__ inline short f2bf(float x) {
    union { __hip_bfloat16 h; short s; } u;
    u.h = __float2bfloat16(x);
    return u.s;
}

__device__ inline void gl_lds16(const void* g, void* l) {
    __builtin_amdgcn_global_load_lds(
        (const __attribute__((address_space(1))) unsigned int*)g,
        (__attribute__((address_space(3))) unsigned int*)l, 16, 0, 0);
}

// ---------------------------------------------------------------------------
// Kernel: x (fp32) -> xb (bf16), flat. 2M elems, 8/thread.
// ---------------------------------------------------------------------------
__global__ __launch_bounds__(256) void cvt_x(const float* __restrict__ x,
                                             short* __restrict__ xb) {
    int idx = (blockIdx.x * 256 + threadIdx.x) * 8;
    float4 a = *(const float4*)(x + idx);
    float4 b = *(const float4*)(x + idx + 4);
    bf16x8 v;
    v[0] = f2bf(a.x); v[1] = f2bf(a.y); v[2] = f2bf(a.z); v[3] = f2bf(a.w);
    v[4] = f2bf(b.x); v[5] = f2bf(b.y); v[6] = f2bf(b.z); v[7] = f2bf(b.w);
    *(bf16x8*)(xb + idx) = v;
}

// ---------------------------------------------------------------------------
// Kernel: generic fp32->bf16 64x64 tile transpose.
//   dst[(g*1024 + r)*1024 + c] = bf16(src[(g*1024 + c)*1024 + r])
// Used for Wt (g = h, grid 4096) AND xbT (g = b, grid 512).
// ---------------------------------------------------------------------------
__global__ __launch_bounds__(256) void cvt_w(const float* __restrict__ W,
                                             short* __restrict__ Wt) {
    __shared__ float T[64][65];
    const int bid = blockIdx.x;
    const int nb = bid & 15, cb = (bid >> 4) & 15, h = bid >> 8;
    const int t = threadIdx.x;
    const int c0 = cb * 64, n0 = nb * 64;
    const float* src = W + (size_t)(h * 1024 + c0) * 1024 + n0;
    {
        const int cl = t >> 4, nl = (t & 15) * 4;
#pragma unroll
        for (int r = 0; r < 4; ++r) {
            float4 v = *(const float4*)(src + (size_t)(cl + r * 16) * 1024 + nl);
            T[cl + r * 16][nl + 0] = v.x;
            T[cl + r * 16][nl + 1] = v.y;
            T[cl + r * 16][nl + 2] = v.z;
            T[cl + r * 16][nl + 3] = v.w;
        }
    }
    __syncthreads();
    {
        short* dst = Wt + (size_t)(h * 1024 + n0) * 1024 + c0;
        const int nl = t >> 3, cl8 = (t & 7) * 8;
#pragma unroll
        for (int r = 0; r < 2; ++r) {
            const int n = nl + r * 32;
            bf16x8 o;
#pragma unroll
            for (int j = 0; j < 8; ++j) o[j] = f2bf(T[cl8 + j][n]);
            *(bf16x8*)(dst + (size_t)n * 1024 + cl8) = o;
        }
    }
}

// ---------------------------------------------------------------------------
// Kernel: attn_po v3 (round-6 proven, ~155 us) — O = softmax(mask(QK^T)/4)@x.
// One 64-row tile per block: 512 blocks = 32 bh * 16 tiles, (512,2) ->
// VGPR cap 128 (measured 120, no spill), 2 blocks/CU. tb pairing keeps
// per-CU total at 17 chunks. V from L2-hot xbT, point-of-use loads.
// Plain bf16 stores to O. [Round-7's (512,1)+V-hoist regressed ~+30 us;
// V-prefetch-in-registers is abandoned: remat at cap128, spill at cap64,
// occupancy loss at cap256.]
// ---------------------------------------------------------------------------
__global__ __launch_bounds__(512, 2) void attn_po(const short* __restrict__ xb,
                                                  const short* __restrict__ xbT,
                                                  short* __restrict__ O) {
    __shared__ short Pb[2][64][72];     // probs bf16, double-buffered
    __shared__ float row_al[2][64];
    __shared__ float row_l[64];
    __shared__ int   flags[2][4];

    const int tid = threadIdx.x;
    const int bh = blockIdx.x & 31;                  // XCD-pinned (b,h)
    const int rest = blockIdx.x >> 5;                // 0..15
    const int tb = (rest < 8) ? rest : 23 - rest;    // pair long+short tiles
    const int b = bh >> 4, h = bh & 15;
    const int lane = tid & 63, q = lane >> 4, l16 = lane & 15;
    const int w = tid >> 6;
    const int g = w & 3;          // QK row-group
    const int nw = w * 128;       // PV channel base
    const short* xbb = xb + ((size_t)b << 20);
    const short* vtb = xbT + ((size_t)b << 20);   // [c][s], s contiguous

    const int t0 = tb * 64;
    const int nch = tb + 1;

    f32x4 acc[4][8];
#pragma unroll
    for (int mt = 0; mt < 4; ++mt)
#pragma unroll
        for (int nt = 0; nt < 8; ++nt) acc[mt][nt] = (f32x4){0.f, 0.f, 0.f, 0.f};
    float m_r[4], l_r[4];
#pragma unroll
    for (int r = 0; r < 4; ++r) { m_r[r] = -3.0e38f; l_r[r] = 0.f; }

    bf16x8 qf[2];
    if (w < 4) {
#pragma unroll
        for (int ks = 0; ks < 2; ++ks)
            qf[ks] = *(const bf16x8*)(xbb + (size_t)(t0 + g * 16 + l16) * 1024 +
                                      h * 64 + ks * 32 + q * 8);
    }

    for (int ci = -1; ci < nch; ++ci) {
        __syncthreads();
        const int cc = ci + 1;
        if (w < 4 && cc < nch) {
            const int s0 = (cc == 0) ? t0 : (cc - 1) * 64;
            const int par = cc & 1;
            // QK^T
            f32x4 sf[4];
#pragma unroll
            for (int st = 0; st < 4; ++st) sf[st] = (f32x4){0.f, 0.f, 0.f, 0.f};
#pragma unroll
            for (int st = 0; st < 4; ++st)
#pragma unroll
                for (int ks = 0; ks < 2; ++ks) {
                    bf16x8 kf = *(const bf16x8*)(xbb +
                        (size_t)(s0 + st * 16 + l16) * 1024 + h * 64 + ks * 32 + q * 8);
                    sf[st] = MFMA16(qf[ks], kf, sf[st]);
                }
            // In-register online softmax (rows q*4+r of group g)
            float mx[4] = {-3.0e38f, -3.0e38f, -3.0e38f, -3.0e38f};
#pragma unroll
            for (int st = 0; st < 4; ++st)
#pragma unroll
                for (int r = 0; r < 4; ++r) {
                    float v = sf[st][r] * 0.25f;
                    if (cc == 0 && (s0 + st * 16 + l16) > (t0 + g * 16 + q * 4 + r))
                        v = -3.0e38f;
                    sf[st][r] = v;
                    mx[r] = fmaxf(mx[r], v);
                }
#pragma unroll
            for (int r = 0; r < 4; ++r) {
                mx[r] = fmaxf(mx[r], __shfl_xor(mx[r], 1));
                mx[r] = fmaxf(mx[r], __shfl_xor(mx[r], 2));
                mx[r] = fmaxf(mx[r], __shfl_xor(mx[r], 4));
                mx[r] = fmaxf(mx[r], __shfl_xor(mx[r], 8));
            }
            float sum[4], al[4];
            int upd = 0;
#pragma unroll
            for (int r = 0; r < 4; ++r) {
                float m_new = fmaxf(m_r[r], mx[r]);
                al[r] = __expf(m_r[r] - m_new);
                upd |= (m_new > m_r[r]) ? 1 : 0;
                m_r[r] = m_new;
                sum[r] = 0.f;
            }
#pragma unroll
            for (int st = 0; st < 4; ++st)
#pragma unroll
                for (int r = 0; r < 4; ++r) {
                    float pv = __expf(sf[st][r] - m_r[r]);
                    sum[r] += pv;
                    Pb[par][g * 16 + q * 4 + r][st * 16 + l16] = f2bf(pv);
                }
#pragma unroll
            for (int r = 0; r < 4; ++r) {
                sum[r] += __shfl_xor(sum[r], 1);
                sum[r] += __shfl_xor(sum[r], 2);
                sum[r] += __shfl_xor(sum[r], 4);
                sum[r] += __shfl_xor(sum[r], 8);
                l_r[r] = l_r[r] * al[r] + sum[r];
            }
            if (l16 == 0) {
#pragma unroll
                for (int r = 0; r < 4; ++r) row_al[par][g * 16 + q * 4 + r] = al[r];
            }
            int any_upd = __any(upd);
            if (lane == 0) flags[par][g] = any_upd;
        }
        if (ci >= 0) {
            const int par = ci & 1;
            // Rescale accumulators only if some row max moved.
            if (flags[par][0] | flags[par][1] | flags[par][2] | flags[par][3]) {
#pragma unroll
                for (int mt = 0; mt < 4; ++mt) {
                    float a0 = row_al[par][mt * 16 + q * 4 + 0];
                    float a1 = row_al[par][mt * 16 + q * 4 + 1];
                    float a2 = row_al[par][mt * 16 + q * 4 + 2];
                    float a3 = row_al[par][mt * 16 + q * 4 + 3];
#pragma unroll
                    for (int nt = 0; nt < 8; ++nt) {
                        acc[mt][nt][0] *= a0;
                        acc[mt][nt][1] *= a1;
                        acc[mt][nt][2] *= a2;
                        acc[mt][nt][3] *= a3;
                    }
                }
            }
            // PV: V-fragments from xbT (L2-hot), point-of-use.
            bf16x8 pf[4][2];
#pragma unroll
            for (int mt = 0; mt < 4; ++mt)
#pragma unroll
                for (int ks = 0; ks < 2; ++ks)
                    pf[mt][ks] = *(bf16x8*)&Pb[par][mt * 16 + l16][ks * 32 + q * 8];
            const int s0p = (ci == 0) ? t0 : (ci - 1) * 64;
#pragma unroll
            for (int nt = 0; nt < 8; ++nt)
#pragma unroll
                for (int ks = 0; ks < 2; ++ks) {
                    bf16x8 vf = *(const bf16x8*)(vtb +
                        (size_t)(nw + nt * 16 + l16) * 1024 + s0p + ks * 32 + q * 8);
#pragma unroll
                    for (int mt = 0; mt < 4; ++mt)
                        acc[mt][nt] = MFMA16(pf[mt][ks], vf, acc[mt][nt]);
                }
        }
    }

    // Epilogue: share row sums, normalize, PLAIN bf16 stores to O.
    if (w < 4 && l16 == 0) {
#pragma unroll
        for (int r = 0; r < 4; ++r) row_l[g * 16 + q * 4 + r] = l_r[r];
    }
    __syncthreads();
    short* ob = O + ((((size_t)(b * 1024 + t0) * 16) + h) << 10);
#pragma unroll
    for (int mt = 0; mt < 4; ++mt) {
        float i0 = 1.f / row_l[mt * 16 + q * 4 + 0];
        float i1 = 1.f / row_l[mt * 16 + q * 4 + 1];
        float i2 = 1.f / row_l[mt * 16 + q * 4 + 2];
        float i3 = 1.f / row_l[mt * 16 + q * 4 + 3];
#pragma unroll
        for (int nt = 0; nt < 8; ++nt) {
            size_t base = (size_t)(mt * 16 + q * 4) * 16384 + nw + nt * 16 + l16;
            ob[base]         = f2bf(acc[mt][nt][0] * i0);
            ob[base + 16384] = f2bf(acc[mt][nt][1] * i1);
            ob[base + 32768] = f2bf(acc[mt][nt][2] * i2);
            ob[base + 49152] = f2bf(acc[mt][nt][3] * i3);
        }
    }
}

// ---------------------------------------------------------------------------
// Kernel: ogemm v4 — out[m][n] += O[m][k] * Wt[k->(h,c)][n].
// Structure = EXACT v1 (176 us proven: split-K 4, BK 32, grid 512, 2 blk/CU)
// + ONE change: bijective XCD-locality swizzle of the block->work mapping.
// Rationale (round-7 evidence): FETCH 301 MB vs ~100 MB ideal at 1.95 TB/s
// accounts for ~154 of the 176 us. Default round-robin dispatch puts the 8
// blocks sharing an O panel on 8 DIFFERENT XCD L2s (8x O fetch) and the 16
// blocks sharing a Wt panel on all XCDs. Remap so XCD x (= blockIdx%8) owns
// kq = x>>1 and m-half = x&1: per-XCD unique = 8 MB O + 8 MB Wt, and the 64
// concurrent blocks per XCD advance k in loose lockstep -> instantaneous
// k-window ~128 KB << 4 MB L2 -> each byte fetched ~once per XCD. Staging
// loads become L2 hits (~200cy vs ~900cy), shortening the per-BK drain.
// Epilogue: fp32 atomicAdd (out pre-zeroed), 8.4M atomics.
// ---------------------------------------------------------------------------
__global__ __launch_bounds__(256, 4) void ogemm(const short* __restrict__ O,
                                                const short* __restrict__ Wt,
                                                float* __restrict__ out) {
    __shared__ short Al[4][128][8];   // [kgrp][m][8k]  8 KiB
    __shared__ short Bl[4][128][8];   // [kgrp][n][8k]  8 KiB

    const int orig = blockIdx.x;                   // HW: XCD = orig & 7
    const int x = orig & 7, j = orig >> 3;         // j in 0..63
    const int kq  = x >> 1;                        // 0..3 (2 XCDs per kq)
    const int m_t = (x & 1) * 8 + (j >> 3);        // 0..15
    const int n_t = j & 7;                         // 0..7 (fast: O reuse)
    const int m0 = m_t * 128, n0 = n_t * 128;
    const int t = threadIdx.x;
    const int lane = t & 63, q = lane >> 4, l16 = lane & 15;
    const int wv = t >> 6;
    const int wm = (wv & 1) * 64, wn = (wv >> 1) * 64;

    const short* Ab = O + (size_t)m0 * 16384;
    const int srow = t & 127, skg = t >> 7;        // staging row / k-group

    char* al_base = (char*)&Al[0][0][0] + (size_t)t * 16;
    char* bl_base = (char*)&Bl[0][0][0] + (size_t)t * 16;

    f32x4 acc[4][4];
#pragma unroll
    for (int i = 0; i < 4; ++i)
#pragma unroll
        for (int j2 = 0; j2 < 4; ++j2) acc[i][j2] = (f32x4){0.f, 0.f, 0.f, 0.f};

    const int kbase = kq * 4096;
    for (int kk = 0; kk < 4096; kk += 32) {
        const int k0 = kbase + kk;
        const int h = k0 >> 10, c0 = k0 & 1023;
        const short* Bb = Wt + ((size_t)h << 20) + (size_t)n0 * 1024 + c0;
        __syncthreads();
        gl_lds16(Ab + (size_t)srow * 16384 + k0 + skg * 8, al_base);
        gl_lds16(Ab + (size_t)srow * 16384 + k0 + (skg + 2) * 8, al_base + 4096);
        gl_lds16(Bb + (size_t)srow * 1024 + skg * 8, bl_base);
        gl_lds16(Bb + (size_t)srow * 1024 + (skg + 2) * 8, bl_base + 4096);
        __syncthreads();
        bf16x8 af[4], bfr[4];
#pragma unroll
        for (int i = 0; i < 4; ++i) af[i] = *(bf16x8*)&Al[q][wm + i * 16 + l16][0];
#pragma unroll
        for (int j2 = 0; j2 < 4; ++j2) bfr[j2] = *(bf16x8*)&Bl[q][wn + j2 * 16 + l16][0];
#pragma unroll
        for (int i = 0; i < 4; ++i)
#pragma unroll
            for (int j2 = 0; j2 < 4; ++j2)
                acc[i][j2] = MFMA16(af[i], bfr[j2], acc[i][j2]);
    }

    // Epilogue: out[m][n] atomic add (split-K partial).
#pragma unroll
    for (int i = 0; i < 4; ++i)
#pragma unroll
        for (int j2 = 0; j2 < 4; ++j2)
#pragma unroll
            for (int r = 0; r < 4; ++r) {
                int m = m0 + wm + i * 16 + q * 4 + r;
                int n = n0 + wn + j2 * 16 + l16;
                atomicAdd(out + (size_t)m * 1024 + n, acc[i][j2][r]);
            }
}

// ---------------------------------------------------------------------------
// Fallback path kernels (round-0 proven): zgemm_fast/zgemm_sm + atomic attn.
// ---------------------------------------------------------------------------
__global__ __launch_bounds__(256, 4) void zgemm_fast(const short* __restrict__ xb,
                                                     const short* __restrict__ Wt,
                                                     short* __restrict__ ZT) {
    __shared__ short Al[4][128][8];
    __shared__ short Bl[4][128][8];

    const int bid = blockIdx.x;
    const int n_t = bid & 7, h = (bid >> 3) & 15, s_t = bid >> 7;
    const int n0 = n_t * 128, s0g = s_t * 128;
    const int t = threadIdx.x;
    const int lane = t & 63, q = lane >> 4, l16 = lane & 15;
    const int wv = t >> 6;
    const int wm = (wv & 1) * 64, wn = (wv >> 1) * 64;

    const short* Ab = Wt + ((size_t)h * 1024 + n0) * 1024;
    const short* Bb = xb + (size_t)s0g * 1024;
    const int srow = t & 127, skg = t >> 7;

    char* al_base = (char*)&Al[0][0][0] + (size_t)t * 16;
    char* bl_base = (char*)&Bl[0][0][0] + (size_t)t * 16;

    f32x4 acc[4][4];
#pragma unroll
    for (int i = 0; i < 4; ++i)
#pragma unroll
        for (int j = 0; j < 4; ++j) acc[i][j] = (f32x4){0.f, 0.f, 0.f, 0.f};

    for (int k0 = 0; k0 < 1024; k0 += 32) {
        __syncthreads();
        gl_lds16(Ab + (size_t)srow * 1024 + k0 + skg * 8, al_base);
        gl_lds16(Ab + (size_t)srow * 1024 + k0 + (skg + 2) * 8, al_base + 4096);
        gl_lds16(Bb + (size_t)srow * 1024 + k0 + skg * 8, bl_base);
        gl_lds16(Bb + (size_t)srow * 1024 + k0 + (skg + 2) * 8, bl_base + 4096);
        __syncthreads();
        bf16x8 af[4], bfr[4];
#pragma unroll
        for (int i = 0; i < 4; ++i) af[i] = *(bf16x8*)&Al[q][wm + i * 16 + l16][0];
#pragma unroll
        for (int j = 0; j < 4; ++j) bfr[j] = *(bf16x8*)&Bl[q][wn + j * 16 + l16][0];
#pragma unroll
        for (int i = 0; i < 4; ++i)
#pragma unroll
            for (int j = 0; j < 4; ++j)
                acc[i][j] = MFMA16(af[i], bfr[j], acc[i][j]);
    }

    const int b = s0g >> 10, s_in0 = s0g & 1023;
    short* zb = ZT + ((size_t)(b * 16 + h) << 20);
#pragma unroll
    for (int i = 0; i < 4; ++i)
#pragma unroll
        for (int j = 0; j < 4; ++j)
#pragma unroll
            for (int r = 0; r < 4; ++r) {
                int n = n0 + wm + i * 16 + q * 4 + r;
                int s = s_in0 + wn + j * 16 + l16;
                zb[(size_t)n * 1024 + s] = f2bf(acc[i][j][r]);
            }
}

#define ZPAD 40

__global__ __launch_bounds__(256, 2) void zgemm_sm(const short* __restrict__ xb,
                                                   const float* __restrict__ W,
                                                   short* __restrict__ ZT) {
    __shared__ short Wts[128 * ZPAD];
    __shared__ short Xs[2][128 * ZPAD];

    const int tid = threadIdx.x;
    const int bs = blockIdx.x & 7;
    const int bn = (blockIdx.x >> 3) & 7;
    const int h  = blockIdx.x >> 6;
    const int s0 = bs * 128, n0 = bn * 128;
    const int lane = tid & 63, q = lane >> 4, l16 = lane & 15;
    const int w = tid >> 6, bw = w >> 1, sh = w & 1;

    f32x4 acc[8][4];
#pragma unroll
    for (int i = 0; i < 8; ++i)
#pragma unroll
        for (int j = 0; j < 4; ++j) acc[i][j] = (f32x4){0.f, 0.f, 0.f, 0.f};

    for (int k0 = 0; k0 < 1024; k0 += 32) {
        __syncthreads();
#pragma unroll
        for (int r = 0; r < 2; ++r) {
            const int c2 = ((tid >> 5) << 1) + (r << 4);
            const float* w0p = W + (size_t)(h * 1024 + k0 + c2) * 1024 + n0;
            const float* w1p = w0p + 1024;
#pragma unroll
            for (int i = 0; i < 4; ++i) {
                const int n = (tid & 31) + (i << 5);
                float wa = w0p[n], wb = w1p[n];
                unsigned u = (unsigned)(unsigned short)f2bf(wa) |
                             ((unsigned)(unsigned short)f2bf(wb) << 16);
                *(unsigned*)&Wts[n * ZPAD + c2] = u;
            }
        }
#pragma unroll
        for (int i = 0; i < 4; ++i) {
            const int id = tid + (i << 8);
            const int b2 = id >> 9, s = (id >> 2) & 127, cg = id & 3;
            bf16x8 v = *(const bf16x8*)(xb + (size_t)b2 * (T_ * C_) +
                                        (size_t)(s0 + s) * 1024 + k0 + cg * 8);
            *(bf16x8*)&Xs[b2][s * ZPAD + cg * 8] = v;
        }
        __syncthreads();

        bf16x8 af[8], bfr[4];
#pragma unroll
        for (int nt = 0; nt < 8; ++nt)
            af[nt] = *(bf16x8*)&Wts[(nt * 16 + l16) * ZPAD + q * 8];
#pragma unroll
        for (int st = 0; st < 4; ++st)
            bfr[st] = *(bf16x8*)&Xs[bw][(sh * 64 + st * 16 + l16) * ZPAD + q * 8];
#pragma unroll
        for (int nt = 0; nt < 8; ++nt)
#pragma unroll
            for (int st = 0; st < 4; ++st)
                acc[nt][st] = MFMA16(af[nt], bfr[st], acc[nt][st]);
    }

    short* zb = ZT + (size_t)(bw * 16 + h) * (1024 * 1024);
#pragma unroll
    for (int nt = 0; nt < 8; ++nt)
#pragma unroll
        for (int st = 0; st < 4; ++st)
#pragma unroll
            for (int r = 0; r < 4; ++r) {
                int n_abs = n0 + nt * 16 + q * 4 + r;
                int s_abs = s0 + sh * 64 + st * 16 + l16;
                zb[(size_t)n_abs * 1024 + s_abs] = f2bf(acc[nt][st][r]);
            }
}

__global__ __launch_bounds__(512, 2) void attn(const short* __restrict__ xb,
                                               const short* __restrict__ ZT,
                                               float* __restrict__ out) {
    __shared__ short Pb[2][64][72];
    __shared__ float row_al[2][64];
    __shared__ float row_l[64];
    __shared__ int   flags[2][4];

    const int tid = threadIdx.x;
    const int bh = blockIdx.x & 31, p = blockIdx.x >> 5;
    const int b = bh >> 4, h = bh & 15;
    const int lane = tid & 63, q = lane >> 4, l16 = lane & 15;
    const int w = tid >> 6;
    const int g = w & 3;
    const int nw = w * 128;
    const short* xbb = xb + ((size_t)b << 20);
    const short* ztb = ZT + ((size_t)(b * 16 + h) << 20);

    const int tiles[2] = { p, 15 - p };
    for (int ti = 0; ti < 2; ++ti) {
        const int tb = tiles[ti];
        const int t0 = tb * 64;
        const int nch = tb + 1;

        f32x4 acc[4][8];
#pragma unroll
        for (int mt = 0; mt < 4; ++mt)
#pragma unroll
            for (int nt = 0; nt < 8; ++nt) acc[mt][nt] = (f32x4){0.f, 0.f, 0.f, 0.f};
        float m_r[4], l_r[4];
#pragma unroll
        for (int r = 0; r < 4; ++r) { m_r[r] = -3.0e38f; l_r[r] = 0.f; }

        bf16x8 qf[2];
        if (w < 4) {
#pragma unroll
            for (int ks = 0; ks < 2; ++ks)
                qf[ks] = *(const bf16x8*)(xbb + (size_t)(t0 + g * 16 + l16) * 1024 +
                                          h * 64 + ks * 32 + q * 8);
        }

        for (int ci = -1; ci < nch; ++ci) {
            __syncthreads();
            const int cc = ci + 1;
            if (w < 4 && cc < nch) {
                const int s0 = (cc == 0) ? t0 : (cc - 1) * 64;
                const int par = cc & 1;
                f32x4 sf[4];
#pragma unroll
                for (int st = 0; st < 4; ++st) sf[st] = (f32x4){0.f, 0.f, 0.f, 0.f};
#pragma unroll
                for (int st = 0; st < 4; ++st)
#pragma unroll
                    for (int ks = 0; ks < 2; ++ks) {
                        bf16x8 kf = *(const bf16x8*)(xbb +
                            (size_t)(s0 + st * 16 + l16) * 1024 + h * 64 + ks * 32 + q * 8);
                        sf[st] = MFMA16(qf[ks], kf, sf[st]);
                    }
                float mx[4] = {-3.0e38f, -3.0e38f, -3.0e38f, -3.0e38f};
#pragma unroll
                for (int st = 0; st < 4; ++st)
#pragma unroll
                    for (int r = 0; r < 4; ++r) {
                        float v = sf[st][r] * 0.25f;
                        if (cc == 0 && (s0 + st * 16 + l16) > (t0 + g * 16 + q * 4 + r))
                            v = -3.0e38f;
                        sf[st][r] = v;
                        mx[r] = fmaxf(mx[r], v);
                    }
#pragma unroll
                for (int r = 0; r < 4; ++r) {
                    mx[r] = fmaxf(mx[r], __shfl_xor(mx[r], 1));
                    mx[r] = fmaxf(mx[r], __shfl_xor(mx[r], 2));
                    mx[r] = fmaxf(mx[r], __shfl_xor(mx[r], 4));
                    mx[r] = fmaxf(mx[r], __shfl_xor(mx[r], 8));
                }
                float sum[4], al[4];
                int upd = 0;
#pragma unroll
                for (int r = 0; r < 4; ++r) {
                    float m_new = fmaxf(m_r[r], mx[r]);
                    al[r] = __expf(m_r[r] - m_new);
                    upd |= (m_new > m_r[r]) ? 1 : 0;
                    m_r[r] = m_new;
                    sum[r] = 0.f;
                }
#pragma unroll
                for (int st = 0; st < 4; ++st)
#pragma unroll
                    for (int r = 0; r < 4; ++r) {
                        float pv = __expf(sf[st][r] - m_r[r]);
                        sum[r] += pv;
                        Pb[par][g * 16 + q * 4 + r][st * 16 + l16] = f2bf(pv);
                    }
#pragma unroll
                for (int r = 0; r < 4; ++r) {
                    sum[r] += __shfl_xor(sum[r], 1);
                    sum[r] += __shfl_xor(sum[r], 2);
                    sum[r] += __shfl_xor(sum[r], 4);
                    sum[r] += __shfl_xor(sum[r], 8);
                    l_r[r] = l_r[r] * al[r] + sum[r];
                }
                if (l16 == 0) {
#pragma unroll
                    for (int r = 0; r < 4; ++r) row_al[par][g * 16 + q * 4 + r] = al[r];
                }
                int any_upd = __any(upd);
                if (lane == 0) flags[par][g] = any_upd;
            }
            if (ci >= 0) {
                const int par = ci & 1;
                if (flags[par][0] | flags[par][1] | flags[par][2] | flags[par][3]) {
#pragma unroll
                    for (int mt = 0; mt < 4; ++mt) {
                        float a0 = row_al[par][mt * 16 + q * 4 + 0];
                        float a1 = row_al[par][mt * 16 + q * 4 + 1];
                        float a2 = row_al[par][mt * 16 + q * 4 + 2];
                        float a3 = row_al[par][mt * 16 + q * 4 + 3];
#pragma unroll
                        for (int nt = 0; nt < 8; ++nt) {
                            acc[mt][nt][0] *= a0;
                            acc[mt][nt][1] *= a1;
                            acc[mt][nt][2] *= a2;
                            acc[mt][nt][3] *= a3;
                        }
                    }
                }
                bf16x8 pf[4][2];
#pragma unroll
                for (int mt = 0; mt < 4; ++mt)
#pragma unroll
                    for (int ks = 0; ks < 2; ++ks)
                        pf[mt][ks] = *(bf16x8*)&Pb[par][mt * 16 + l16][ks * 32 + q * 8];
                const int s0p = (ci == 0) ? t0 : (ci - 1) * 64;
#pragma unroll
                for (int nt = 0; nt < 8; ++nt)
#pragma unroll
                    for (int ks = 0; ks < 2; ++ks) {
                        bf16x8 vf = *(const bf16x8*)(ztb +
                            (size_t)(nw + nt * 16 + l16) * 1024 + s0p + ks * 32 + q * 8);
#pragma unroll
                        for (int mt = 0; mt < 4; ++mt)
                            acc[mt][nt] = MFMA16(pf[mt][ks], vf, acc[mt][nt]);
                    }
            }
        }

        if (w < 4 && l16 == 0) {
#pragma unroll
            for (int r = 0; r < 4; ++r) row_l[g * 16 + q * 4 + r] = l_r[r];
        }
        __syncthreads();
#pragma unroll
        for (int mt = 0; mt < 4; ++mt) {
            float i0 = 1.f / row_l[mt * 16 + q * 4 + 0];
            float i1 = 1.f / row_l[mt * 16 + q * 4 + 1];
            float i2 = 1.f / row_l[mt * 16 + q * 4 + 2];
            float i3 = 1.f / row_l[mt * 16 + q * 4 + 3];
#pragma unroll
            for (int nt = 0; nt < 8; ++nt) {
                size_t base = (size_t)(b * 1024 + t0 + mt * 16 + q * 4) * 1024 +
                              nw + nt * 16 + l16;
                atomicAdd(out + base,            acc[mt][nt][0] * i0);
                atomicAdd(out + base + 1024,     acc[mt][nt][1] * i1);
                atomicAdd(out + base + 2048,     acc[mt][nt][2] * i2);
                atomicAdd(out + base + 3072,     acc[mt][nt][3] * i3);
            }
        }
        __syncthreads();
    }
}

// ---------------------------------------------------------------------------
extern "C" void kernel_launch(void* const* d_in, const int* in_sizes, int n_in,
                              void* d_out, int out_size, void* d_ws, size_t ws_size,
                              hipStream_t stream) {
    const float* x = (const float*)d_in[0];
    // d_in[1] (mask) recomputed analytically.
    const float* W = (const float*)d_in[2];
    float* out = (float*)d_out;

    hipMemsetAsync(d_out, 0, (size_t)B_ * T_ * C_ * sizeof(float), stream);

    if (ws_size >= (size_t)104 * 1024 * 1024) {
        // O = P@x per head (plain stores), then one long-K GEMM.
        // ws layout (shorts): xb[0,2M) xbT[2M,4M) Wt[4M,20M) O[20M,52M)
        short* xb  = (short*)d_ws;
        short* xbT = xb + (size_t)2 * 1024 * 1024;
        short* Wt  = xb + (size_t)4 * 1024 * 1024;
        short* O   = xb + (size_t)20 * 1024 * 1024;

        cvt_x<<<(B_ * T_ * C_) / (256 * 8), 256, 0, stream>>>(x, xb);
        cvt_w<<<B_ * 16 * 16, 256, 0, stream>>>(x, xbT);   // xbT[b][c][s]
        cvt_w<<<16 * 16 * 16, 256, 0, stream>>>(W, Wt);    // Wt[h][n][c]
        attn_po<<<512, 512, 0, stream>>>(xb, xbT, O);
        ogemm<<<4 * 16 * 8, 256, 0, stream>>>(O, Wt, out);
    } else {
        // Fallback: round-0 proven pipeline.
        short* xb = (short*)d_ws;                              // 4 MiB
        short* ZT = (short*)d_ws + (size_t)B_ * T_ * C_;       // 64 MiB
        short* Wt = ZT + (size_t)B_ * H_ * 1024 * 1024;        // 32 MiB

        const bool big_ws = ws_size >= (size_t)100 * 1024 * 1024;
        cvt_x<<<(B_ * T_ * C_) / (256 * 8), 256, 0, stream>>>(x, xb);
        if (big_ws) {
            cvt_w<<<16 * 16 * 16, 256, 0, stream>>>(W, Wt);
            zgemm_fast<<<16 * 16 * 8, 256, 0, stream>>>(xb, Wt, ZT);
        } else {
            zgemm_sm<<<H_ * 8 * 8, 256, 0, stream>>>(xb, W, ZT);
        }
        attn<<<256, 512, 0, stream>>>(xb, ZT, out);
    }
}